// Round 9
// baseline (42.416 us; speedup 1.0000x reference)
//
#include <hip/hip_runtime.h>
#include <math.h>

#define BATCH 16
#define TQL   2048
#define TKL   1024
#define DDEC  256
#define DENC  256
#define DATT  128
#define WIN   3

// workspace layout (floats):
//   kq : 48*256  @ 0       (Wq^T-folded keys:  s_j = q . kq + kb)
//   vo : 48*256  @ 12288   (Wo-folded values:  ctx@Wo^T = 32 * sum a_j vo_j)
//   kb : 48      @ 24576
#define WS_KQ 0
#define WS_VO (48*DDEC)
#define WS_KB (2*48*DDEC)

#define NZBLK 2048   // zero-fill blocks; 134217728 B / 2048 = 65536 B per block

// ---------------------------------------------------------------------------
// Kernel 1 (unchanged from R6): blocks 0..47 = folded-weight precompute;
// blocks 48..2095 stream zeros over attn (pure-store phase, ~7 TB/s).
// ---------------------------------------------------------------------------
__global__ __launch_bounds__(256) void pre_and_zero(
    const float* __restrict__ keys, const float* __restrict__ values,
    const float* __restrict__ Wk, const float* __restrict__ bk,
    const float* __restrict__ Wv, const float* __restrict__ bv,
    const float* __restrict__ Wq, const float* __restrict__ bq,
    const float* __restrict__ Wo, const int* __restrict__ pidx,
    float* __restrict__ ws, float* __restrict__ attn)
{
    const int t = threadIdx.x;

    if (blockIdx.x >= 48) {
        const int zb = blockIdx.x - 48;
        float4* p = (float4*)attn + (size_t)zb * 4096;   // 4096 float4 per block
        const float4 z4 = make_float4(0.0f, 0.0f, 0.0f, 0.0f);
        #pragma unroll
        for (int i = 0; i < 16; ++i) p[i * 256 + t] = z4;
        return;
    }

    const int blk = blockIdx.x;            // 0..47
    const int b = blk / WIN, j = blk % WIN;
    const int prev = pidx[0];
    const int col = prev + j;
    const bool valid = (col >= 0) && (col < TKL);

    __shared__ float ksh[DENC];
    __shared__ float vsh[DENC];
    __shared__ float kwsh[DATT];
    __shared__ float vwsh[DATT];

    {
        size_t base = ((size_t)b * TKL + (valid ? col : 0)) * DENC + t;
        ksh[t] = valid ? keys[base]   : 0.0f;
        vsh[t] = valid ? values[base] : 0.0f;
    }
    __syncthreads();

    if (t < DATT) {
        const float4* wrow = (const float4*)(Wk + (size_t)t * DENC);
        float acc = 0.0f;
        #pragma unroll 8
        for (int k4 = 0; k4 < DENC / 4; ++k4) {
            float4 w = wrow[k4];
            acc += w.x * ksh[k4*4+0] + w.y * ksh[k4*4+1]
                 + w.z * ksh[k4*4+2] + w.w * ksh[k4*4+3];
        }
        kwsh[t] = acc + bk[t];
    } else {
        const int c = t - DATT;
        const float4* wrow = (const float4*)(Wv + (size_t)c * DENC);
        float acc = 0.0f;
        #pragma unroll 8
        for (int k4 = 0; k4 < DENC / 4; ++k4) {
            float4 w = wrow[k4];
            acc += w.x * vsh[k4*4+0] + w.y * vsh[k4*4+1]
                 + w.z * vsh[k4*4+2] + w.w * vsh[k4*4+3];
        }
        vwsh[c] = acc + bv[c];
    }
    __syncthreads();

    float accq = 0.0f, acco = 0.0f;
    const float4* worow = (const float4*)(Wo + (size_t)t * DATT);
    #pragma unroll 4
    for (int c4 = 0; c4 < DATT / 4; ++c4) {
        float4 w = worow[c4];
        acco += w.x * vwsh[c4*4+0] + w.y * vwsh[c4*4+1]
              + w.z * vwsh[c4*4+2] + w.w * vwsh[c4*4+3];
        accq += kwsh[c4*4+0] * Wq[(size_t)(c4*4+0) * DDEC + t]
              + kwsh[c4*4+1] * Wq[(size_t)(c4*4+1) * DDEC + t]
              + kwsh[c4*4+2] * Wq[(size_t)(c4*4+2) * DDEC + t]
              + kwsh[c4*4+3] * Wq[(size_t)(c4*4+3) * DDEC + t];
    }
    ws[WS_KQ + blk * DDEC + t] = accq;
    ws[WS_VO + blk * DDEC + t] = acco;

    if (t < 64) {
        float pb = bq[t] * kwsh[t] + bq[t + 64] * kwsh[t + 64];
        #pragma unroll
        for (int off = 32; off > 0; off >>= 1) pb += __shfl_xor(pb, off, 64);
        if (t == 0) ws[WS_KB + blk] = pb;
    }
}

// ---------------------------------------------------------------------------
// Kernel 2: 64-lane-per-row layout. Each wave owns 8 rows; operands are
// 1 float4/lane (7 f4 = 28 VGPR, no intra-wave redundancy), all 8 q-row
// loads (1 KB coalesced each) issued upfront. Low VGPR -> 4-5 waves/SIMD.
// After the 64-lane butterfly the softmax weights are wave-uniform, so
// lanes 0/1 write the attn window patches directly.
// ---------------------------------------------------------------------------
__device__ __forceinline__ float winval(int ww, float w0, float w1, float w2) {
    float v = (ww == 0) ? w0 : ((ww == 1) ? w1 : ((ww == 2) ? w2 : 0.0f));
    return (ww >= 0 && ww < WIN) ? v : 0.0f;
}

#define ROWS_PER_WAVE 8

__global__ __launch_bounds__(256) void attn_out(
    const float* __restrict__ query, const float* __restrict__ bo,
    const int* __restrict__ pidx, const float* __restrict__ ws,
    float* __restrict__ out, float* __restrict__ attn)
{
    const int t    = threadIdx.x;
    const int lane = t & 63;
    const int wid  = t >> 6;                 // wave 0..3
    const int blk  = blockIdx.x;             // 0..1023
    const int b    = blk >> 6;               // 64 blocks per batch
    const int base = b * WIN;
    const int prev = pidx[0];
    const int row0 = blk * (4 * ROWS_PER_WAVE) + wid * ROWS_PER_WAVE;

    // ---- issue all 8 q-row loads first (8 KB in flight per wave) ----
    const float4* qp = (const float4*)query;
    float4 q[ROWS_PER_WAVE];
    #pragma unroll
    for (int r = 0; r < ROWS_PER_WAVE; ++r)
        q[r] = qp[(size_t)(row0 + r) * 64 + lane];

    // ---- operands: 1 f4 per lane each (wave covers all 256 dims) ----
    const float4* kq4 = (const float4*)(ws + WS_KQ) + (size_t)base * 64;
    const float4* vo4 = (const float4*)(ws + WS_VO) + (size_t)base * 64;
    const float4 K0 = kq4[      lane];
    const float4 K1 = kq4[ 64 + lane];
    const float4 K2 = kq4[128 + lane];
    const float4 V0 = vo4[      lane];
    const float4 V1 = vo4[ 64 + lane];
    const float4 V2 = vo4[128 + lane];
    const float4 B4 = ((const float4*)bo)[lane];
    const float kb0 = ws[WS_KB + base + 0];
    const float kb1 = ws[WS_KB + base + 1];
    const float kb2 = ws[WS_KB + base + 2];

    // ---- window float4 indices (uniform) ----
    int lo = prev < 0 ? 0 : prev;
    int hi = prev + (WIN - 1) > TKL - 1 ? TKL - 1 : prev + (WIN - 1);
    int f0 = -1, f1 = -1;
    if (lo <= hi) { f0 = lo >> 2; f1 = hi >> 2; }

    const bool v0 = (prev + 0 >= 0) && (prev + 0 < TKL);
    const bool v1 = (prev + 1 >= 0) && (prev + 1 < TKL);
    const bool v2 = (prev + 2 >= 0) && (prev + 2 < TKL);

    const float CTX_SCALE = 32.0f;            // Tk * sqrt(1/Tk) = sqrt(1024)
    const float RSQ2 = 0.70710678118654752f;  // sqrt(0.5)
    const float NEG = -3.0e38f;

    #pragma unroll
    for (int r = 0; r < ROWS_PER_WAVE; ++r) {
        const int row = row0 + r;
        const float4 qq = q[r];

        float p0 = qq.x*K0.x + qq.y*K0.y + qq.z*K0.z + qq.w*K0.w;
        float p1 = qq.x*K1.x + qq.y*K1.y + qq.z*K1.z + qq.w*K1.w;
        float p2 = qq.x*K2.x + qq.y*K2.y + qq.z*K2.z + qq.w*K2.w;

        #pragma unroll
        for (int off = 32; off > 0; off >>= 1) {
            p0 += __shfl_xor(p0, off, 64);
            p1 += __shfl_xor(p1, off, 64);
            p2 += __shfl_xor(p2, off, 64);
        }

        float s0 = v0 ? (p0 + kb0) : NEG;
        float s1 = v1 ? (p1 + kb1) : NEG;
        float s2 = v2 ? (p2 + kb2) : NEG;

        const float m  = fmaxf(s0, fmaxf(s1, s2));
        const float e0 = v0 ? __expf(s0 - m) : 0.0f;
        const float e1 = v1 ? __expf(s1 - m) : 0.0f;
        const float e2 = v2 ? __expf(s2 - m) : 0.0f;
        const float inv = 1.0f / (e0 + e1 + e2);
        const float w0 = e0 * inv, w1 = e1 * inv, w2 = e2 * inv;

        float4 o;
        o.x = (CTX_SCALE * (w0*V0.x + w1*V1.x + w2*V2.x) + B4.x + qq.x) * RSQ2;
        o.y = (CTX_SCALE * (w0*V0.y + w1*V1.y + w2*V2.y) + B4.y + qq.y) * RSQ2;
        o.z = (CTX_SCALE * (w0*V0.z + w1*V1.z + w2*V2.z) + B4.z + qq.z) * RSQ2;
        o.w = (CTX_SCALE * (w0*V0.w + w1*V1.w + w2*V2.w) + B4.w + qq.w) * RSQ2;
        ((float4*)(out + (size_t)row * DDEC))[lane] = o;

        // window patch: scores are wave-uniform after the butterfly
        if (f0 >= 0 && lane == 0) {
            const int c0 = f0 * 4;
            float4 pz;
            pz.x = winval(c0 + 0 - prev, w0, w1, w2);
            pz.y = winval(c0 + 1 - prev, w0, w1, w2);
            pz.z = winval(c0 + 2 - prev, w0, w1, w2);
            pz.w = winval(c0 + 3 - prev, w0, w1, w2);
            ((float4*)(attn + (size_t)row * TKL))[f0] = pz;
        }
        if (f1 != f0 && lane == 1) {
            const int c0 = f1 * 4;
            float4 pz;
            pz.x = winval(c0 + 0 - prev, w0, w1, w2);
            pz.y = winval(c0 + 1 - prev, w0, w1, w2);
            pz.z = winval(c0 + 2 - prev, w0, w1, w2);
            pz.w = winval(c0 + 3 - prev, w0, w1, w2);
            ((float4*)(attn + (size_t)row * TKL))[f1] = pz;
        }
    }
}

extern "C" void kernel_launch(void* const* d_in, const int* in_sizes, int n_in,
                              void* d_out, int out_size, void* d_ws, size_t ws_size,
                              hipStream_t stream)
{
    const float* query  = (const float*)d_in[0];
    const float* keys   = (const float*)d_in[1];
    const float* values = (const float*)d_in[2];
    const float* Wq     = (const float*)d_in[3];
    const float* bq     = (const float*)d_in[4];
    const float* Wk     = (const float*)d_in[5];
    const float* bk     = (const float*)d_in[6];
    const float* Wv     = (const float*)d_in[7];
    const float* bv     = (const float*)d_in[8];
    const float* Wo     = (const float*)d_in[9];
    const float* bo     = (const float*)d_in[10];
    const int*   pidx   = (const int*)d_in[11];

    float* ws   = (float*)d_ws;
    float* out  = (float*)d_out;
    float* attn = out + (size_t)BATCH * TQL * DDEC;

    pre_and_zero<<<48 + NZBLK, 256, 0, stream>>>(keys, values, Wk, bk, Wv, bv,
                                                 Wq, bq, Wo, pidx, ws, attn);
    attn_out<<<BATCH * TQL / 32, 256, 0, stream>>>(query, bo, pidx, ws, out, attn);
}